// Round 3
// baseline (221.210 us; speedup 1.0000x reference)
//
#include <hip/hip_runtime.h>

// out[n,c,h,w]:
//   c in [0,64)    : x[n, c+64, (h-1)&63, w]
//   c in [64,128)  : x[n, c-64, (h+1)&63, w]
//   c in [128,192) : x[n, c+64, h, (w-1)&63]
//   c in [192,256) : x[n, c-64, h, (w+1)&63]
//
// N=32, C=256, H=64, W=64.  vec4 flat index v bits: [0:3]=w4, [4:9]=h, [10:17]=c, [18:]=n.
// Each WAVE owns 256 consecutive vec4s (16 h-rows, one channel -> c,g wave-uniform).
// Each THREAD does 4 vec4s, one per 64-vec4 stripe (k=0..3):
//   - every load/store instruction is dense across the wave (64 lanes x 16 B = 1 KB)
//   - 4 independent load->store chains per thread (MLP), 4x fewer waves than r2
// w-wrap element for g=2,3 comes from the 16-lane row-group neighbor via __shfl.

typedef float vf4 __attribute__((ext_vector_type(4)));

__global__ __launch_bounds__(256) void swap_kernel(const float* __restrict__ x,
                                                   float* __restrict__ out) {
    const int t     = blockIdx.x * blockDim.x + threadIdx.x;
    const int l     = t & 63;             // lane
    const int wid   = t >> 6;             // global wave id
    const int vbase = (wid << 8) + l;     // wave covers vec4s [wid*256, wid*256+256)

    // wave-uniform: channel, batch, group
    const int c = (vbase >> 10) & 255;
    const int n = vbase >> 18;
    const int g = c >> 6;
    const int src_c = (g == 0 || g == 2) ? (c + 64) : (c - 64);
    const int cbase = (n << 20) + (src_c << 12);  // float offset of source channel

    const int w4 = l & 15;                // vec4 index within the 64-float row
    const int lp = (l - 1) & 15;          // group-relative prev lane (w-1 wrap)
    const int ln = (l + 1) & 15;          // group-relative next lane (w+1 wrap)

#pragma unroll 4
    for (int k = 0; k < 4; ++k) {
        const int v = vbase + (k << 6);   // stays inside the wave's 256-chunk
        const int h = (v >> 4) & 63;
        vf4 r;
        if (g == 0) {
            r = __builtin_nontemporal_load(reinterpret_cast<const vf4*>(
                    x + cbase + (((h - 1) & 63) << 6) + (w4 << 2)));
        } else if (g == 1) {
            r = __builtin_nontemporal_load(reinterpret_cast<const vf4*>(
                    x + cbase + (((h + 1) & 63) << 6) + (w4 << 2)));
        } else if (g == 2) {
            // out[w] = row[(w-1)&63]
            vf4 f = __builtin_nontemporal_load(reinterpret_cast<const vf4*>(
                    x + cbase + (h << 6) + (w4 << 2)));
            float prv = __shfl(f.w, lp, 16);   // row[w0-1] from prev row-group lane
            r = (vf4){prv, f.x, f.y, f.z};
        } else {
            // out[w] = row[(w+1)&63]
            vf4 f = __builtin_nontemporal_load(reinterpret_cast<const vf4*>(
                    x + cbase + (h << 6) + (w4 << 2)));
            float nx = __shfl(f.x, ln, 16);    // row[w0+4] from next row-group lane
            r = (vf4){f.y, f.z, f.w, nx};
        }
        __builtin_nontemporal_store(r, reinterpret_cast<vf4*>(out + (v << 2)));
    }
}

extern "C" void kernel_launch(void* const* d_in, const int* in_sizes, int n_in,
                              void* d_out, int out_size, void* d_ws, size_t ws_size,
                              hipStream_t stream) {
    const float* x   = (const float*)d_in[0];
    float*       out = (float*)d_out;
    // total vec4 = 32*256*64*16 = 8,388,608; 4 per thread -> 2,097,152 threads
    const int block = 256;
    const int grid  = (32 * 256 * 64 * 16) / 4 / block;  // 8192
    swap_kernel<<<grid, block, 0, stream>>>(x, out);
}